// Round 5
// baseline (214.011 us; speedup 1.0000x reference)
//
#include <hip/hip_runtime.h>
#include <cstdint>

typedef __attribute__((ext_vector_type(8)))  short bf16x8;   // 8 x bf16 (4 VGPR)
typedef __attribute__((ext_vector_type(16))) float f32x16;   // MFMA 32x32 acc
typedef __attribute__((ext_vector_type(2)))  float f32x2;
typedef __attribute__((ext_vector_type(4)))  int   i32x4;

__device__ __forceinline__ unsigned short f2bf(float x) {    // RNE fp32->bf16
  unsigned u = __float_as_uint(x);
  u += 0x7fffu + ((u >> 16) & 1u);
  return (unsigned short)(u >> 16);
}
__device__ __forceinline__ float bf2f(unsigned short h) {
  return __uint_as_float(((unsigned)h) << 16);
}
__device__ __forceinline__ float silu_f(float v) {
  return v * __builtin_amdgcn_rcpf(1.0f + __expf(-v));
}
// pack two fp32 -> bf16x2 dword (lo = first arg)
__device__ __forceinline__ unsigned pk2bf(float lo, float hi) {
#if defined(__has_builtin)
#if __has_builtin(__builtin_amdgcn_cvt_pk_bf16_f32)
  auto v = __builtin_amdgcn_cvt_pk_bf16_f32(lo, hi);
  unsigned u; __builtin_memcpy(&u, &v, 4); return u;
#else
  return ((unsigned)f2bf(hi) << 16) | (unsigned)f2bf(lo);
#endif
#else
  return ((unsigned)f2bf(hi) << 16) | (unsigned)f2bf(lo);
#endif
}
// v_perm lane-local byte select
__device__ __forceinline__ unsigned lo_pack(unsigned x, unsigned y) {
  return __builtin_amdgcn_perm(y, x, 0x05040100u);
}
__device__ __forceinline__ unsigned hi_pack(unsigned x, unsigned y) {
  return __builtin_amdgcn_perm(y, x, 0x07060302u);
}
// async global->LDS, 16B/lane; lds ptr is wave-uniform base (+lane*16 implied)
__device__ __forceinline__ void gl_lds16(const unsigned short* g, unsigned short* l) {
  __builtin_amdgcn_global_load_lds(
      (const __attribute__((address_space(1))) unsigned int*)g,
      (__attribute__((address_space(3))) unsigned int*)l, 16, 0, 0);
}
// stage `chunks` 16B-chunks (chunks % 64 == 0) into lds_w
__device__ __forceinline__ void stage(const unsigned short* src, unsigned short* lds_w,
                                      const int tid, const int w, const int chunks) {
  for (int it = 0; it * 512 < chunks; ++it) {
    const int ci = it * 512 + tid;
    if (ci < chunks)                              // wave-uniform split (chunks%64==0)
      gl_lds16(src + ci * 8, lds_w + (it * 512 + w * 64) * 8);
  }
}

// ---- pack W0/W1/W2 into MFMA B-frag order via LDS transpose (coalesced R+W).
// dest layout: [layer][g(64 cols)][t(32-col tile)][kt][lane][8], K0 padded 134->144.
// One block per k-slab (16 rows x 256 cols): 9 (L0) + 16 (L1) + 16 (L2) = 41 blocks.
__global__ void pack_kernel(const float* __restrict__ W0, const float* __restrict__ W1,
                            const float* __restrict__ W2,
                            unsigned short* __restrict__ packW) {
  __shared__ float ldsF[16][257];
  const int s = blockIdx.x, tid = threadIdx.x;
  const float* W; int KT, kmax, base, kt;
  if (s < 9)       { W = W0; KT = 9;  kmax = 134; base = 0;      kt = s; }
  else if (s < 25) { W = W1; KT = 16; kmax = 256; base = 36864;  kt = s - 9; }
  else             { W = W2; KT = 16; kmax = 256; base = 102400; kt = s - 25; }
  const int k0 = kt * 16;
#pragma unroll
  for (int i = 0; i < 8; ++i) {                 // 512 thr x 8 = 16 x 256 floats
    const int idx = i * 512 + tid;
    const int kl = idx >> 8, col = idx & 255;
    const int kg = k0 + kl;
    ldsF[kl][col] = (kg < kmax) ? W[kg * 256 + col] : 0.0f;   // coalesced rows
  }
  __syncthreads();
  const int g = tid >> 7, t = (tid >> 6) & 1, lane = tid & 63;
  const int col = g * 64 + t * 32 + (lane & 31);
  const int kb = 8 * (lane >> 5);
  unsigned u0 = pk2bf(ldsF[kb + 0][col], ldsF[kb + 1][col]);
  unsigned u1 = pk2bf(ldsF[kb + 2][col], ldsF[kb + 3][col]);
  unsigned u2 = pk2bf(ldsF[kb + 4][col], ldsF[kb + 5][col]);
  unsigned u3 = pk2bf(ldsF[kb + 6][col], ldsF[kb + 7][col]);
  unsigned short* dst = packW + base + g * (KT * 1024) + t * (KT * 512) + kt * 512 + lane * 8;
  i32x4 v = { (int)u0, (int)u1, (int)u2, (int)u3 };
  *(i32x4*)dst = v;                             // coalesced 16B writes
}

// ---------------- one GCN layer, fully fused per graph ----------------
// Node mapping: A-row m holds node 32w + sig(m), sig(m)=(m&3)+4((m>>3)&3)+16((m>>2)&1).
// => C/D reg r of lane (q,c) holds node 32w + 16q + r  (16 consecutive nodes per half).
// Per group: tile0 B from double-buffered LDS (prefetched via global_load_lds at the
// top of the PREVIOUS group's body), tile1 B streamed from global (L1/L2) -> both
// memory pipes carry half the B traffic. Exactly one __syncthreads per group.
template <int KT, int LAYER>
__device__ __forceinline__ void gcn_layer(
    const int tid, const int w, const int lane, const int q, const int c, const int sig,
    const unsigned short* __restrict__ packL,
    const unsigned short* __restrict__ nextL, const int nextChunks,
    const float* __restrict__ BIAS,
    const bf16x8* Aold, bf16x8* Anew,
    unsigned short* wbuf, unsigned short* bnd,
    unsigned int* scr3_w, float* poolw) {
#pragma unroll
  for (int g = 0; g < 4; ++g) {
    // prefetch next tile0 into the other LDS buffer; target buffer is dead since
    // barrier(g-1) (all waves done reading it), DMA overlaps this group's MFMA,
    // and this group's barrier vmcnt(0) drain completes it before first use.
    if (g < 3)           stage(packL + (g + 1) * (KT * 1024), wbuf + ((g + 1) & 1) * 8192,
                               tid, w, KT * 64);
    else if (nextChunks) stage(nextL, wbuf + ((g + 1) & 1) * 8192, tid, w, nextChunks);

    const unsigned short* srcg = packL + g * (KT * 1024);
    f32x16 acc0, acc1;
#pragma unroll
    for (int i = 0; i < 16; ++i) { acc0[i] = 0.f; acc1[i] = 0.f; }
    {
      const bf16x8* wb0 = (const bf16x8*)(wbuf + (g & 1) * 8192); // tile0 from LDS
      const bf16x8* wb1 = (const bf16x8*)(srcg + KT * 512);       // tile1 from global
#pragma unroll
      for (int kt = 0; kt < KT; ++kt) {
        bf16x8 b0 = wb0[kt * 64 + lane];
        bf16x8 b1 = wb1[kt * 64 + lane];
        acc0 = __builtin_amdgcn_mfma_f32_32x32x16_bf16(Aold[kt], b0, acc0, 0, 0, 0);
        acc1 = __builtin_amdgcn_mfma_f32_32x32x16_bf16(Aold[kt], b1, acc1, 0, 0, 0);
      }
    }

    // publish wave-boundary s rows into bnd parity buffer:
    // entry w*2+0 = first node (32w), entry w*2+1 = last node (32w+31)
    unsigned short* bndp = bnd + (g & 1) * 2048;
    if (q == 0) { bndp[(w * 2 + 0) * 64 + c]      = f2bf(acc0[0]);
                  bndp[(w * 2 + 0) * 64 + 32 + c] = f2bf(acc1[0]); }
    else        { bndp[(w * 2 + 1) * 64 + c]      = f2bf(acc0[15]);
                  bndp[(w * 2 + 1) * 64 + 32 + c] = f2bf(acc1[15]); }
    __syncthreads();   // single per-group barrier: bnd(g) + staged tile0(g+1) visible

    // cross-half edge values (node 15 <-> node 16 of the wave's 32-node stripe)
    const float e0t0  = __shfl_xor(acc0[0], 32);
    const float e0t1  = __shfl_xor(acc1[0], 32);
    const float e15t0 = __shfl_xor(acc0[15], 32);
    const float e15t1 = __shfl_xor(acc1[15], 32);
    const float bp0 = bf2f(bndp[(((w + 7) & 7) * 2 + 1) * 64 + c]);        // node 32w-1
    const float bp1 = bf2f(bndp[(((w + 7) & 7) * 2 + 1) * 64 + 32 + c]);
    const float bn0 = bf2f(bndp[(((w + 1) & 7) * 2 + 0) * 64 + c]);        // node 32w+32
    const float bn1 = bf2f(bndp[(((w + 1) & 7) * 2 + 0) * 64 + 32 + c]);
    const float bias0 = BIAS[g * 64 + c], bias1 = BIAS[g * 64 + 32 + c];
    const float T = 0.33333333333f;
    float ps0 = 0.f, ps1 = 0.f;
#pragma unroll
    for (int r = 0; r < 16; ++r) {
      float pr0, pr1, nx0, nx1;
      if (r > 0)       { pr0 = acc0[r - 1]; pr1 = acc1[r - 1]; }
      else             { pr0 = q ? e15t0 : bp0; pr1 = q ? e15t1 : bp1; }
      if (r < 15)      { nx0 = acc0[r + 1]; nx1 = acc1[r + 1]; }
      else             { nx0 = q ? bn0 : e0t0; nx1 = q ? bn1 : e0t1; }
      f32x2 v2;
      v2.x = (pr0 + acc0[r] + nx0) * T + bias0;
      v2.y = (pr1 + acc1[r] + nx1) * T + bias1;
      f32x2 ex; ex.x = __expf(-v2.x); ex.y = __expf(-v2.y);
      f32x2 den = ex + 1.0f;
      f32x2 y2;
      y2.x = v2.x * __builtin_amdgcn_rcpf(den.x);
      y2.y = v2.y * __builtin_amdgcn_rcpf(den.y);
      if constexpr (LAYER == 2) { ps0 += y2.x; ps1 += y2.y; }
      else {
        scr3_w[(16 * q + r) * 34 + c] = pk2bf(y2.x, y2.y);  // row = true node-local idx
      }
    }

    if constexpr (LAYER == 2) {
      ps0 += __shfl_xor(ps0, 32);
      ps1 += __shfl_xor(ps1, 32);
      if (q == 0) { poolw[w * 256 + g * 64 + c]      = ps0;
                    poolw[w * 256 + g * 64 + 32 + c] = ps1; }
    } else {
      // rebuild A-frags for next layer (same-wave DS, in-order -> no barrier);
      // A-row m=c needs node-local sig(c)
      const unsigned int* sb = scr3_w + sig * 34;
      uint2 d0 = *(const uint2*)(sb + 8 * q + 0);
      uint2 d1 = *(const uint2*)(sb + 8 * q + 2);
      uint2 d2 = *(const uint2*)(sb + 8 * q + 4);
      uint2 d3 = *(const uint2*)(sb + 8 * q + 6);
      uint2 e0 = *(const uint2*)(sb + 16 + 8 * q + 0);
      uint2 e1 = *(const uint2*)(sb + 16 + 8 * q + 2);
      uint2 e2 = *(const uint2*)(sb + 16 + 8 * q + 4);
      uint2 e3 = *(const uint2*)(sb + 16 + 8 * q + 6);
      i32x4 f0 = { (int)lo_pack(d0.x, d0.y), (int)lo_pack(d1.x, d1.y),
                   (int)lo_pack(d2.x, d2.y), (int)lo_pack(d3.x, d3.y) };
      i32x4 f1 = { (int)lo_pack(e0.x, e0.y), (int)lo_pack(e1.x, e1.y),
                   (int)lo_pack(e2.x, e2.y), (int)lo_pack(e3.x, e3.y) };
      i32x4 f2v = { (int)hi_pack(d0.x, d0.y), (int)hi_pack(d1.x, d1.y),
                    (int)hi_pack(d2.x, d2.y), (int)hi_pack(d3.x, d3.y) };
      i32x4 f3 = { (int)hi_pack(e0.x, e0.y), (int)hi_pack(e1.x, e1.y),
                   (int)hi_pack(e2.x, e2.y), (int)hi_pack(e3.x, e3.y) };
      Anew[g * 4 + 0] = __builtin_bit_cast(bf16x8, f0);
      Anew[g * 4 + 1] = __builtin_bit_cast(bf16x8, f1);
      Anew[g * 4 + 2] = __builtin_bit_cast(bf16x8, f2v);
      Anew[g * 4 + 3] = __builtin_bit_cast(bf16x8, f3);
    }
  }
}

// ---------------- main fused kernel: 1 block = 1 graph, 8 waves x 32 nodes ----------
__global__ __launch_bounds__(512, 2) void poly_kernel(
    const float* __restrict__ x, const float* __restrict__ t,
    const float* __restrict__ tw, const float* __restrict__ tb,
    const unsigned short* __restrict__ packW,
    const float* __restrict__ B0, const float* __restrict__ B1,
    const float* __restrict__ B2, float* __restrict__ out) {
  __shared__ __align__(16) unsigned short wbuf[2 * 8192];  // 32 KiB tile0 double buffer
  __shared__ __align__(16) unsigned short bnd[4096];       //  8 KiB boundary (2 par x 8w x 2 x 64)
  __shared__ __align__(16) unsigned int   scr3[8 * 1088];  // 34 KiB per-wave packed transpose
  __shared__ __align__(16) unsigned short temb_sh[160];    // padded time embedding (bf16)

  const int tid = threadIdx.x;
  const int w = tid >> 6, lane = tid & 63;
  const int q = lane >> 5, c = lane & 31;
  const int b = blockIdx.x;
  // sig(c): node-local index held by A-row m=c
  const int sig = (c & 3) + 4 * ((c >> 3) & 3) + 16 * ((c >> 2) & 1);

  // kick off layer-0 group-0 tile0 staging immediately (overlaps the time MLP;
  // completed by the MLP's barriers' vmcnt drains)
  stage(packW, wbuf, tid, w, 9 * 64);

  // ---- fused time MLP: temb = silu(sinemb(t[b]) @ tw + tb), padded [0x6, ., 0x10] ----
  {
    float* e_sh = (float*)bnd;        // 128 floats
    float* part = (float*)scr3;       // 512 float partials
    if (tid < 128) {
      const float tv = t[b];
      const int i = tid & 63;
      const float f = expf(-0.14619588396823767f * (float)i);  // log(1e4)/63
      const float ang = tv * f;
      e_sh[tid] = (tid < 64) ? sinf(ang) : cosf(ang);
    }
    __syncthreads();
    {
      const int j = tid & 127, p = tid >> 7;   // 4-way k-split over the block
      float a = 0.f;
#pragma unroll 8
      for (int kk = 0; kk < 32; ++kk) {
        const int k = p * 32 + kk;
        a += e_sh[k] * tw[k * 128 + j];
      }
      part[tid] = a;
    }
    __syncthreads();
    if (tid < 128) {
      const float a = tb[tid] + part[tid] + part[128 + tid] + part[256 + tid] + part[384 + tid];
      temb_sh[6 + tid] = f2bf(silu_f(a));
      if (tid < 6)  temb_sh[tid] = 0;
      if (tid < 10) temb_sh[134 + tid] = 0;
    }
    __syncthreads();
  }

  // build layer-0 A fragments: [coords(2), pe(4), temb(128), pad0(10)] = K 144
  bf16x8 A0[9], A1[16], A2[16];
  {
#pragma unroll
    for (int kt = 0; kt < 9; ++kt)
      A0[kt] = *(const bf16x8*)(temb_sh + kt * 16 + q * 8);
    if (q == 0) {  // k=0..5 live in q==0 lanes of k-tile 0; A-row m=c holds node 32w+sig
      const int n = w * 32 + sig;
      const float2 xy = ((const float2*)x)[b * 256 + n];
      const float th = 0.024543692605870074f * (float)n;   // 2*pi/256
      A0[0][0] = (short)f2bf(xy.x);
      A0[0][1] = (short)f2bf(xy.y);
      A0[0][2] = (short)f2bf(sinf(th));
      A0[0][3] = (short)f2bf(cosf(th));
      A0[0][4] = (short)f2bf(sinf(2.f * th));
      A0[0][5] = (short)f2bf(cosf(2.f * th));
    }
  }

  unsigned int* scr3_w = scr3 + w * 1088;
  float* poolw = (float*)scr3;   // layer-2 per-wave pool partials (transpose dead by then)
  gcn_layer< 9, 0>(tid, w, lane, q, c, sig, packW,          packW + 36864,  16 * 64,
                   B0, A0, A1, wbuf, bnd, scr3_w, poolw);
  gcn_layer<16, 1>(tid, w, lane, q, c, sig, packW + 36864,  packW + 102400, 16 * 64,
                   B1, A1, A2, wbuf, bnd, scr3_w, poolw);
  gcn_layer<16, 2>(tid, w, lane, q, c, sig, packW + 102400, nullptr,        0,
                   B2, A2, A1, wbuf, bnd, scr3_w, poolw);

  __syncthreads();
  if (tid < 256) {
    float s = 0.f;
#pragma unroll
    for (int ww = 0; ww < 8; ++ww) s += poolw[ww * 256 + tid];
    out[b * 256 + tid] = s * (1.f / 256.f);
  }
}

// ---------------- launch ----------------
extern "C" void kernel_launch(void* const* d_in, const int* in_sizes, int n_in,
                              void* d_out, int out_size, void* d_ws, size_t ws_size,
                              hipStream_t stream) {
  const float* x  = (const float*)d_in[0];
  const float* t  = (const float*)d_in[1];
  const float* tw = (const float*)d_in[2];
  const float* tb = (const float*)d_in[3];
  const float* W0 = (const float*)d_in[4];
  const float* b0 = (const float*)d_in[5];
  const float* W1 = (const float*)d_in[6];
  const float* b1 = (const float*)d_in[7];
  const float* W2 = (const float*)d_in[8];
  const float* b2 = (const float*)d_in[9];

  unsigned short* packW = (unsigned short*)d_ws;   // 167936 shorts
  float* out = (float*)d_out;

  pack_kernel<<<41, 512, 0, stream>>>(W0, W1, W2, packW);
  poly_kernel<<<1024, 512, 0, stream>>>(x, t, tw, tb, packW, b0, b1, b2, out);
}